// Round 14
// baseline (1148.128 us; speedup 1.0000x reference)
//
#include <hip/hip_runtime.h>
#include <hip/hip_bf16.h>
#include <cstdint>
#include <cstddef>

namespace {
constexpr int B_ = 16;
constexpr int N_ = 4096;
constexpr int D_ = 64;
constexpr int M_ = 1024;
constexpr int S_ = 32;
constexpr int NROWS_ = B_ * M_ * S_;        // 524288
constexpr int TPB_ = 256;
constexpr int NBLKM_ = NROWS_ / TPB_;       // 2048 (fallback, R=1)
constexpr int NBLK2_ = NROWS_ / (2 * TPB_); // 1024 (R=2)
constexpr float RR_ = 0.04f;

// k_pre block roles (NO fps in this kernel)
constexpr int PRE_E  = 128;   // 65536 rows / 512
constexpr int PRE_SQ = 128;   // 65536 pts / 512
constexpr int PRE_NB = PRE_E + PRE_SQ + 1;  // 257

// ws offsets (bytes)
constexpr size_t OFF_SQN  = 0;                                    // 262144
constexpr size_t OFF_FPS  = 262144;                               // 65536
constexpr size_t OFF_BALL = 327680;                               // 2097152
constexpr size_t OFF_W0T  = 2424832;                              // 17152
constexpr size_t OFF_W1T  = OFF_W0T + 67 * 64 * 4;                // 16384
constexpr size_t OFF_W2T  = OFF_W1T + 64 * 64 * 4;                // 32768
constexpr size_t OFF_PART = OFF_W2T + 64 * 128 * 4;               // 2048*256*4
constexpr size_t OFF_BNP  = OFF_PART + (size_t)NBLKM_ * 256 * 4;  // 3072
constexpr size_t OFF_E    = (OFF_BNP + 3072 + 255) & ~(size_t)255;
constexpr size_t E_SZ     = (size_t)B_ * N_ * 64 * 4;             // 16,777,216
constexpr size_t OFF_D    = OFF_E + E_SZ;
constexpr size_t D_SZ     = (size_t)B_ * M_ * 64 * 4;             // 4,194,304
constexpr size_t OFF_H1   = OFF_D + D_SZ;
constexpr size_t H1F_SZ   = (size_t)NROWS_ * 64 * 4;              // 134,217,728
constexpr size_t H1H_SZ   = (size_t)NROWS_ * 64 * 2;              // 67,108,864
constexpr size_t NEED_A   = OFF_H1 + H1F_SZ;                      // ~152.4 MiB
constexpr size_t NEED_B   = OFF_H1 + H1H_SZ;                      // ~88.4 MiB
}

// non-contractible multiply (separately-rounded product), scheduler-friendly
__device__ __forceinline__ float mul_nr(float a, float b) {
    float p = a * b;
    asm("" : "+v"(p));
    return p;
}
// volatile variant kept for the PROVEN-bitwise decision kernels (zero-risk)
__device__ __forceinline__ float mul_nf(float a, float b) {
    float p = a * b;
    asm volatile("" : "+v"(p));
    return p;
}

// DPP lane move (VALU-rate cross-lane)
template <int CTRL>
__device__ __forceinline__ float dpp_movf(float x) {
    return __int_as_float(
        __builtin_amdgcn_update_dpp(0, __float_as_int(x), CTRL, 0xF, 0xF, true));
}
__device__ __forceinline__ float xor_exch(float x, int k) {
    if (k == 0) return dpp_movf<0xB1>(x);   // quad_perm [1,0,3,2]
    if (k == 1) return dpp_movf<0x4E>(x);   // quad_perm [2,3,0,1]
    return __shfl_xor(x, 1 << k);
}

// ---------------------------------------------------------------- fold reduce
__device__ __forceinline__ float fold_sum_wave(float* cur, int lane) {
#pragma unroll
    for (int k = 0; k < 6; k++) {
        const bool hi = (lane >> k) & 1;
#pragma unroll
        for (int m = 0; m < (32 >> k); m++) {
            const float a = cur[2 * m], b = cur[2 * m + 1];
            const float keep = hi ? b : a;
            const float give = hi ? a : b;
            const float got = xor_exch(give, k);
            cur[m] = keep + got;
        }
    }
    return cur[0];
}
__device__ __forceinline__ float fold_sum32(float* cur, int lane) {
#pragma unroll
    for (int k = 0; k < 5; k++) {
        const bool hi = (lane >> k) & 1;
#pragma unroll
        for (int m = 0; m < (16 >> k); m++) {
            const float a = cur[2 * m], b = cur[2 * m + 1];
            const float keep = hi ? b : a;
            const float give = hi ? a : b;
            const float got = xor_exch(give, k);
            cur[m] = keep + got;
        }
    }
    return cur[0];
}
__device__ __forceinline__ float fold_max32(float* cur, int lane) {
#pragma unroll
    for (int k = 0; k < 5; k++) {
        const bool hi = (lane >> k) & 1;
#pragma unroll
        for (int m = 0; m < (16 >> k); m++) {
            const float a = cur[2 * m], b = cur[2 * m + 1];
            const float keep = hi ? b : a;
            const float give = hi ? a : b;
            const float got = xor_exch(give, k);
            cur[m] = fmaxf(keep, got);
        }
    }
    return cur[0];
}
__device__ __forceinline__ float fold_min32(float* cur, int lane) {
#pragma unroll
    for (int k = 0; k < 5; k++) {
        const bool hi = (lane >> k) & 1;
#pragma unroll
        for (int m = 0; m < (16 >> k); m++) {
            const float a = cur[2 * m], b = cur[2 * m + 1];
            const float keep = hi ? b : a;
            const float give = hi ? a : b;
            const float got = xor_exch(give, k);
            cur[m] = fminf(keep, got);
        }
    }
    return cur[0];
}
__device__ __forceinline__ void fold_max_half(float* cur, int lane, float& r0, float& r1) {
#pragma unroll
    for (int k = 0; k < 5; k++) {
        const bool hi = (lane >> k) & 1;
#pragma unroll
        for (int m = 0; m < (32 >> k); m++) {
            const float a = cur[2 * m], b = cur[2 * m + 1];
            const float keep = hi ? b : a;
            const float give = hi ? a : b;
            const float got = xor_exch(give, k);
            cur[m] = fmaxf(keep, got);
        }
    }
    r0 = cur[0]; r1 = cur[1];
}

// bf16 pack/unpack (RNE)
__device__ __forceinline__ unsigned short f2bf(float f) {
    __hip_bfloat16 h = __float2bfloat16(f);
    return *reinterpret_cast<unsigned short*>(&h);
}
__device__ __forceinline__ float bf2f(unsigned short u) {
    __hip_bfloat16 h = *reinterpret_cast<__hip_bfloat16*>(&u);
    return __bfloat162float(h);
}

// ---------------------------------------------------------------- FPS
// v4: own-point coords loaded from GLOBAL and pinned to VGPRs via opaque asm —
// the compiler was re-reading px/py/pz from the LDS pts[] copy every iteration
// (24 ds_read/thread/iter ≈ 1100 cyc/CU/iter, 3x the VALU floor; VGPR stayed
// 40 even with launch_bounds(512,2)). pts[] LDS is kept ONLY for the uniform
// centroid broadcast pts[3*far]. Arithmetic bit-identical.
__global__ __launch_bounds__(512, 2) void k_fps(const float* __restrict__ xyz,
                                                int* __restrict__ fps_idx) {
    const int b = blockIdx.x, t = threadIdx.x;
    const int lane = t & 63, w = t >> 6;
    const float* xb = xyz + (size_t)b * N_ * 3;
    __shared__ float pts[N_ * 3];
    __shared__ unsigned long long slots[2][8];
    for (int i = t; i < N_ * 3; i += 512) pts[i] = xb[i];

    const int n0 = t * 8;
    float px[8], py[8], pz[8], dist[8];
#pragma unroll
    for (int k = 0; k < 8; k++) {
        px[k] = xb[3 * (n0 + k)];          // GLOBAL load (not the LDS copy)
        py[k] = xb[3 * (n0 + k) + 1];
        pz[k] = xb[3 * (n0 + k) + 2];
        dist[k] = 1e10f;
    }
#pragma unroll
    for (int k = 0; k < 8; k++) {
        // opaque definition: cannot be rematerialized from memory -> stays in VGPR
        asm("" : "+v"(px[k]), "+v"(py[k]), "+v"(pz[k]));
    }
    __syncthreads();

    int far = 0;
    for (int i = 0; i < M_; i++) {
        if (t == 0) fps_idx[b * M_ + i] = far;
        const float c0 = pts[3 * far], c1 = pts[3 * far + 1], c2 = pts[3 * far + 2];
        float bestv = -1.0f; int bestn = n0;
#pragma unroll
        for (int k = 0; k < 8; k++) {
            const float d0 = px[k] - c0, d1 = py[k] - c1, d2 = pz[k] - c2;
            const float dd = (mul_nr(d0, d0) + mul_nr(d1, d1)) + mul_nr(d2, d2);
            const float dm = fminf(dist[k], dd);
            dist[k] = dm;
            if (dm > bestv) { bestv = dm; bestn = n0 + k; }
        }
        float m = bestv;
        m = fmaxf(m, dpp_movf<0x111>(m));
        m = fmaxf(m, dpp_movf<0x112>(m));
        m = fmaxf(m, dpp_movf<0x114>(m));
        m = fmaxf(m, dpp_movf<0x118>(m));
        m = fmaxf(m, dpp_movf<0x142>(m));
        m = fmaxf(m, dpp_movf<0x143>(m));
        const float wmax = __int_as_float(
            __builtin_amdgcn_readlane(__float_as_int(m), 63));
        const unsigned long long mk = __ballot(bestv == wmax);
        const int src = __ffsll((long long)mk) - 1;
        const int wn = __builtin_amdgcn_readlane(bestn, src);
        if (lane == 0)
            slots[i & 1][w] =
                ((unsigned long long)__float_as_uint(wmax) << 32) | (unsigned)(~wn);
        __syncthreads();
        const unsigned long long* sl = slots[i & 1];
        const unsigned long long s0 = sl[0], s1 = sl[1], s2 = sl[2], s3 = sl[3];
        const unsigned long long s4 = sl[4], s5 = sl[5], s6 = sl[6], s7 = sl[7];
        const unsigned long long a0 = s0 > s1 ? s0 : s1;
        const unsigned long long a1 = s2 > s3 ? s2 : s3;
        const unsigned long long a2 = s4 > s5 ? s4 : s5;
        const unsigned long long a3 = s6 > s7 ? s6 : s7;
        const unsigned long long b0 = a0 > a1 ? a0 : a1;
        const unsigned long long b1 = a2 > a3 ? a2 : a3;
        const unsigned long long bb = b0 > b1 ? b0 : b1;
        far = (int)(~(unsigned)bb);
    }
}

// ================================================================ k_pre bodies (no FPS here)
// E[n][o] = points[n]·W0p + xyz[n]·W0x  (self-transposes W0 from global)
__device__ void e_body(const float* __restrict__ points, const float* __restrict__ xyz,
                       const float* __restrict__ W0, float* __restrict__ E, int eb) {
    __shared__ float w0[67 * 64];
    const int t = threadIdx.x;
    for (int i = t; i < 67 * 64; i += 512) {
        const int c = i >> 6, o = i & 63;
        w0[i] = W0[o * 67 + c];
    }
    __syncthreads();
    const int n = eb * 512 + t;               // 0..65535
    const float* prow = points + (size_t)n * 64;
    float h[64];
#pragma unroll
    for (int o = 0; o < 64; o++) h[o] = 0.f;
#pragma unroll
    for (int c = 0; c < 64; c += 4) {
        const float4 xv = *reinterpret_cast<const float4*>(prow + c);
        const float xs[4] = {xv.x, xv.y, xv.z, xv.w};
#pragma unroll
        for (int j = 0; j < 4; j++) {
            const float xc = xs[j];
            const float* wr = w0 + (c + j) * 64;
#pragma unroll
            for (int o = 0; o < 64; o++) h[o] = fmaf(xc, wr[o], h[o]);
        }
    }
    const float x0 = xyz[(size_t)n * 3], x1 = xyz[(size_t)n * 3 + 1], x2 = xyz[(size_t)n * 3 + 2];
#pragma unroll
    for (int o = 0; o < 64; o++) h[o] = fmaf(x0, w0[64 * 64 + o], h[o]);
#pragma unroll
    for (int o = 0; o < 64; o++) h[o] = fmaf(x1, w0[65 * 64 + o], h[o]);
#pragma unroll
    for (int o = 0; o < 64; o++) h[o] = fmaf(x2, w0[66 * 64 + o], h[o]);
    float4* dst = (float4*)(E + (size_t)n * 64);
#pragma unroll
    for (int j = 0; j < 16; j++)
        dst[j] = make_float4(h[4 * j], h[4 * j + 1], h[4 * j + 2], h[4 * j + 3]);
}

__device__ void sq_body(const float* __restrict__ xyz, float* __restrict__ sqn, int sb) {
    const int i = sb * 512 + threadIdx.x;     // 0..65535
    const float x = xyz[3 * i], y = xyz[3 * i + 1], z = xyz[3 * i + 2];
    sqn[i] = (mul_nf(x, x) + mul_nf(y, y)) + mul_nf(z, z);
}

__device__ void wt_body(const float* __restrict__ W0, const float* __restrict__ W1,
                        const float* __restrict__ W2, float* __restrict__ W0T,
                        float* __restrict__ W1T, float* __restrict__ W2T) {
    const int t = threadIdx.x;
    for (int i = t; i < 67 * 64; i += 512) { const int c = i >> 6, o = i & 63; W0T[i] = W0[o * 67 + c]; }
    for (int i = t; i < 64 * 64; i += 512) { const int c = i >> 6, o = i & 63; W1T[i] = W1[o * 64 + c]; }
    for (int i = t; i < 64 * 128; i += 512) { const int c = i >> 7, o = i & 127; W2T[i] = W2[o * 64 + c]; }
}

// fused: E ∥ sqnorm ∥ weight-transpose (mutually independent; no FPS)
__global__ __launch_bounds__(512) void k_pre(
    const float* __restrict__ xyz, const float* __restrict__ points,
    const float* __restrict__ W0, const float* __restrict__ W1,
    const float* __restrict__ W2, float* __restrict__ E, float* __restrict__ sqn,
    float* __restrict__ W0T, float* __restrict__ W1T, float* __restrict__ W2T,
    int do_e) {
    const int blk = blockIdx.x;
    if (blk < PRE_E) { if (do_e) e_body(points, xyz, W0, E, blk); return; }
    if (blk < PRE_E + PRE_SQ) { sq_body(xyz, sqn, blk - PRE_E); return; }
    wt_body(W0, W1, W2, W0T, W1T, W2T);
}

// ---------------------------------------------------------------- newxyz + D + ball (fused; wave per q)
__global__ __launch_bounds__(256) void k_ndball(const float* __restrict__ xyz,
                                                const float* __restrict__ sqn,
                                                const int* __restrict__ fps_idx,
                                                const float* __restrict__ W0T,
                                                float* __restrict__ newxyz,
                                                float* __restrict__ Dq,
                                                int* __restrict__ ball, int do_d) {
    const int w = threadIdx.x >> 6, lane = threadIdx.x & 63;
    const int q = blockIdx.x * 4 + w;
    const int b = q >> 10;
    __shared__ int buf[4][32];
    const float* xb = xyz + (size_t)b * N_ * 3;
    const float* sb = sqn + (size_t)b * N_;
    const int f = fps_idx[q];
    const float* p = xyz + ((size_t)b * N_ + f) * 3;
    const float q0 = p[0], q1 = p[1], q2 = p[2];
    if (lane == 0) {
        newxyz[3 * q] = q0; newxyz[3 * q + 1] = q1; newxyz[3 * q + 2] = q2;
    }
    if (do_d) {
        const float wa = W0T[64 * 64 + lane];
        const float wb = W0T[65 * 64 + lane];
        const float wc = W0T[66 * 64 + lane];
        Dq[(size_t)q * 64 + lane] = fmaf(q2, wc, fmaf(q1, wb, q0 * wa));
    }
    const float sq = sb[f];

    int cnt = 0;
    for (int base = 0; base < N_ && cnt < 32; base += 64) {
        const int n = base + lane;
        const float p0 = xb[3 * n], p1 = xb[3 * n + 1], p2 = xb[3 * n + 2];
        float dot = fmaf(q2, p2, fmaf(q1, p1, q0 * p0));   // ascending FMA (proven)
        float tt = -2.0f * dot;
        tt = tt + sq;
        tt = tt + sb[n];
        const bool pred = !(tt > RR_);
        const unsigned long long mask = __ballot(pred);
        const int pos = cnt + __popcll(mask & ((1ull << lane) - 1ull));
        if (pred && pos < 32) buf[w][pos] = n;
        cnt += (int)__popcll(mask);
    }
    __syncthreads();
    if (lane < 32) {
        int e = buf[w][(lane < cnt) ? lane : 0];
        ball[(size_t)q * 32 + lane] = e;
    }
}

// ================================================================ helpers
__device__ __forceinline__ void stage_w(float* dst, const float* __restrict__ src,
                                        int n, int t) {
    for (int i = t; i < n; i += TPB_) dst[i] = src[i];
}

template <int NCH>
__device__ __forceinline__ void bn_relu(float* x, const float* __restrict__ bnp, int base) {
#pragma unroll
    for (int o = 0; o < NCH; o++)
        x[o] = fmaxf(0.f, fmaf(x[o], bnp[base + o], bnp[base + 128 + o]));
}

__device__ __forceinline__ void load_h0(float* x, const float* __restrict__ E,
                                        const float* __restrict__ Dq,
                                        const int* __restrict__ ball, int r) {
    const int b = r >> 15, q = r >> 5;
    const int g = ball[r];
    const float4* e = (const float4*)(E + ((size_t)(b * N_) + g) * 64);
    const float4* d = (const float4*)(Dq + (size_t)q * 64);
#pragma unroll
    for (int j = 0; j < 16; j++) {
        const float4 ev = e[j]; const float4 dv = d[j];
        x[4 * j + 0] = ev.x - dv.x; x[4 * j + 1] = ev.y - dv.y;
        x[4 * j + 2] = ev.z - dv.z; x[4 * j + 3] = ev.w - dv.w;
    }
}

__device__ __forceinline__ void h1_load_f32(float* x, const float* buf, int r) {
    const float4* src = (const float4*)(buf + (size_t)r * 64);
#pragma unroll
    for (int j = 0; j < 16; j++) {
        const float4 v = src[j];
        x[4 * j] = v.x; x[4 * j + 1] = v.y; x[4 * j + 2] = v.z; x[4 * j + 3] = v.w;
    }
}
__device__ __forceinline__ void h1_load_bf(float* x, const unsigned short* buf, int r) {
    const ushort4* src = (const ushort4*)(buf + (size_t)r * 64);
#pragma unroll
    for (int j = 0; j < 16; j++) {
        const ushort4 v = src[j];
        x[4 * j] = bf2f(v.x); x[4 * j + 1] = bf2f(v.y);
        x[4 * j + 2] = bf2f(v.z); x[4 * j + 3] = bf2f(v.w);
    }
}

// ================================================================ MLP stages (R=2)
__global__ __launch_bounds__(TPB_, 2) void k_s0(
    const float* __restrict__ E, const float* __restrict__ Dq,
    const int* __restrict__ ball, float* __restrict__ partials) {
    const int t = threadIdx.x, lane = t & 63, w = t >> 6;
    const int r0 = blockIdx.x * 512 + t, r1 = r0 + 256;
    __shared__ float ssum[4][64], ssq[4][64];
    float x0[64], x1[64];
    load_h0(x0, E, Dq, ball, r0);
    load_h0(x1, E, Dq, ball, r1);
#pragma unroll
    for (int i = 0; i < 64; i++) {
        const float sv_ = x0[i] + x1[i];
        x1[i] = x0[i] * x0[i] + x1[i] * x1[i];
        x0[i] = sv_;
    }
    const float sv = fold_sum_wave(x0, lane);
    const float qv = fold_sum_wave(x1, lane);
    ssum[w][lane] = sv; ssq[w][lane] = qv;
    __syncthreads();
    if (t < 64) {
        float* dst = partials + (size_t)blockIdx.x * 256;
        dst[t] = ssum[0][t] + ssum[1][t] + ssum[2][t] + ssum[3][t];
        dst[128 + t] = ssq[0][t] + ssq[1][t] + ssq[2][t] + ssq[3][t];
    }
}

template <int HST>
__global__ __launch_bounds__(TPB_, 2) void k_s1(
    const float* __restrict__ E, const float* __restrict__ Dq,
    const int* __restrict__ ball, const float* __restrict__ W1T,
    const float* __restrict__ bnp, float* __restrict__ partials,
    float* __restrict__ h1f, unsigned short* __restrict__ h1h) {
    __shared__ float w1[64 * 64];
    __shared__ float ssum[4][64], ssq[4][64];
    const int t = threadIdx.x, lane = t & 63, w = t >> 6;
    stage_w(w1, W1T, 64 * 64, t);
    const int r0 = blockIdx.x * 512 + t, r1 = r0 + 256;
    float x0[64], x1[64];
    load_h0(x0, E, Dq, ball, r0);
    bn_relu<64>(x0, bnp, 0);
    load_h0(x1, E, Dq, ball, r1);
    bn_relu<64>(x1, bnp, 0);
    __syncthreads();

#pragma unroll
    for (int tile = 0; tile < 2; tile++) {
        float a0[32], a1[32];
#pragma unroll
        for (int o = 0; o < 32; o++) { a0[o] = 0.f; a1[o] = 0.f; }
#pragma unroll
        for (int c = 0; c < 64; c++) {
            const float* wr = w1 + c * 64 + tile * 32;
            const float xc0 = x0[c], xc1 = x1[c];
#pragma unroll
            for (int o = 0; o < 32; o++) {
                a0[o] = fmaf(xc0, wr[o], a0[o]);
                a1[o] = fmaf(xc1, wr[o], a1[o]);
            }
        }
        if constexpr (HST == 1) {
            float4* d0 = (float4*)(h1f + (size_t)r0 * 64 + tile * 32);
            float4* d1 = (float4*)(h1f + (size_t)r1 * 64 + tile * 32);
#pragma unroll
            for (int j = 0; j < 8; j++) {
                d0[j] = make_float4(a0[4 * j], a0[4 * j + 1], a0[4 * j + 2], a0[4 * j + 3]);
                d1[j] = make_float4(a1[4 * j], a1[4 * j + 1], a1[4 * j + 2], a1[4 * j + 3]);
            }
        } else {
            ushort4* d0 = (ushort4*)(h1h + (size_t)r0 * 64 + tile * 32);
            ushort4* d1 = (ushort4*)(h1h + (size_t)r1 * 64 + tile * 32);
#pragma unroll
            for (int j = 0; j < 8; j++) {
                ushort4 v0, v1;
                v0.x = f2bf(a0[4 * j]); v0.y = f2bf(a0[4 * j + 1]);
                v0.z = f2bf(a0[4 * j + 2]); v0.w = f2bf(a0[4 * j + 3]);
                v1.x = f2bf(a1[4 * j]); v1.y = f2bf(a1[4 * j + 1]);
                v1.z = f2bf(a1[4 * j + 2]); v1.w = f2bf(a1[4 * j + 3]);
                d0[j] = v0; d1[j] = v1;
            }
        }
#pragma unroll
        for (int o = 0; o < 32; o++) {
            const float sv_ = a0[o] + a1[o];
            a1[o] = a0[o] * a0[o] + a1[o] * a1[o];
            a0[o] = sv_;
        }
        float sv = fold_sum32(a0, lane); sv += __shfl_xor(sv, 32);
        float qv = fold_sum32(a1, lane); qv += __shfl_xor(qv, 32);
        if (lane < 32) { ssum[w][tile * 32 + lane] = sv; ssq[w][tile * 32 + lane] = qv; }
    }
    __syncthreads();
    if (t < 64) {
        float* dst = partials + (size_t)blockIdx.x * 256;
        dst[t] = ssum[0][t] + ssum[1][t] + ssum[2][t] + ssum[3][t];
        dst[128 + t] = ssq[0][t] + ssq[1][t] + ssq[2][t] + ssq[3][t];
    }
}

template <int HLD>
__global__ __launch_bounds__(TPB_, 2) void k_s2(
    const float* __restrict__ h1f, const unsigned short* __restrict__ h1h,
    const float* __restrict__ W2T, const float* __restrict__ bnp,
    float* __restrict__ partials, float* __restrict__ maxb,
    float* __restrict__ minb) {
    __shared__ float w2[64 * 128];
    __shared__ float ssum[4][128], ssq[4][128];
    const int t = threadIdx.x, lane = t & 63, w = t >> 6;
    stage_w(w2, W2T, 64 * 128, t);
    const int r0 = blockIdx.x * 512 + t, r1 = r0 + 256;
    float x0[64], x1[64];
    if constexpr (HLD == 1) { h1_load_f32(x0, h1f, r0); h1_load_f32(x1, h1f, r1); }
    else { h1_load_bf(x0, h1h, r0); h1_load_bf(x1, h1h, r1); }
    bn_relu<64>(x0, bnp, 256);
    bn_relu<64>(x1, bnp, 256);
    __syncthreads();

    const int q0 = blockIdx.x * 16 + w * 2 + (lane >> 5);
#pragma unroll
    for (int tile = 0; tile < 4; tile++) {
        float a0[32], a1[32];
#pragma unroll
        for (int o = 0; o < 32; o++) { a0[o] = 0.f; a1[o] = 0.f; }
#pragma unroll
        for (int c = 0; c < 64; c++) {
            const float* wr = w2 + c * 128 + tile * 32;
            const float xc0 = x0[c], xc1 = x1[c];
#pragma unroll
            for (int o = 0; o < 32; o++) {
                a0[o] = fmaf(xc0, wr[o], a0[o]);
                a1[o] = fmaf(xc1, wr[o], a1[o]);
            }
        }
        {
            float c0[32];
#pragma unroll
            for (int o = 0; o < 32; o++) c0[o] = a0[o];
            const float mx = fold_max32(c0, lane);
#pragma unroll
            for (int o = 0; o < 32; o++) c0[o] = a0[o];
            const float mn = fold_min32(c0, lane);
            maxb[(size_t)q0 * 128 + tile * 32 + (lane & 31)] = mx;
            minb[(size_t)q0 * 128 + tile * 32 + (lane & 31)] = mn;
#pragma unroll
            for (int o = 0; o < 32; o++) c0[o] = a1[o];
            const float mx1 = fold_max32(c0, lane);
#pragma unroll
            for (int o = 0; o < 32; o++) c0[o] = a1[o];
            const float mn1 = fold_min32(c0, lane);
            maxb[(size_t)(q0 + 8) * 128 + tile * 32 + (lane & 31)] = mx1;
            minb[(size_t)(q0 + 8) * 128 + tile * 32 + (lane & 31)] = mn1;
        }
#pragma unroll
        for (int o = 0; o < 32; o++) {
            const float sv_ = a0[o] + a1[o];
            a1[o] = a0[o] * a0[o] + a1[o] * a1[o];
            a0[o] = sv_;
        }
        float sv = fold_sum32(a0, lane); sv += __shfl_xor(sv, 32);
        float qv = fold_sum32(a1, lane); qv += __shfl_xor(qv, 32);
        if (lane < 32) { ssum[w][tile * 32 + lane] = sv; ssq[w][tile * 32 + lane] = qv; }
    }
    __syncthreads();
    if (t < 128) {
        float* dst = partials + (size_t)blockIdx.x * 256;
        dst[t] = ssum[0][t] + ssum[1][t] + ssum[2][t] + ssum[3][t];
        dst[128 + t] = ssq[0][t] + ssq[1][t] + ssq[2][t] + ssq[3][t];
    }
}

// S3: elementwise epilogue (monotone-fma max/min select; bit-identical)
__global__ __launch_bounds__(256) void k_s3m(
    const float* __restrict__ maxb, const float* __restrict__ minb,
    const float* __restrict__ bnp, float* __restrict__ out_np) {
    const int i = blockIdx.x * 256 + threadIdx.x;
    const int ch = i & 127;
    const float sc = bnp[512 + ch], sh = bnp[512 + 128 + ch];
    const float h = (sc >= 0.f) ? maxb[i] : minb[i];
    out_np[i] = fmaxf(0.f, fmaf(h, sc, sh));
}

// ================================================================ fallback (R=1 recompute)
__device__ __forceinline__ void g0_row(
    const float* __restrict__ points, const float* __restrict__ xyz,
    const float* __restrict__ newxyz, const int* __restrict__ ball,
    const float* w0, int r, float* h0) {
    const int b = r >> 15;
    const int q = r >> 5;
    const int g = ball[r];
    const float* prow = points + ((size_t)(b * N_) + g) * D_;
    const float xg0 = xyz[((size_t)b * N_ + g) * 3 + 0] - newxyz[(size_t)q * 3 + 0];
    const float xg1 = xyz[((size_t)b * N_ + g) * 3 + 1] - newxyz[(size_t)q * 3 + 1];
    const float xg2 = xyz[((size_t)b * N_ + g) * 3 + 2] - newxyz[(size_t)q * 3 + 2];
#pragma unroll
    for (int o = 0; o < 64; o++) h0[o] = 0.f;
#pragma unroll
    for (int c = 0; c < 64; c += 4) {
        const float4 xv = *reinterpret_cast<const float4*>(prow + c);
        const float xs[4] = {xv.x, xv.y, xv.z, xv.w};
#pragma unroll
        for (int j = 0; j < 4; j++) {
            const float xc = xs[j];
            const float* wr = w0 + (c + j) * 64;
#pragma unroll
            for (int o = 0; o < 64; o++) h0[o] = fmaf(xc, wr[o], h0[o]);
        }
    }
#pragma unroll
    for (int o = 0; o < 64; o++) h0[o] = fmaf(xg0, w0[64 * 64 + o], h0[o]);
#pragma unroll
    for (int o = 0; o < 64; o++) h0[o] = fmaf(xg1, w0[65 * 64 + o], h0[o]);
#pragma unroll
    for (int o = 0; o < 64; o++) h0[o] = fmaf(xg2, w0[66 * 64 + o], h0[o]);
}
__device__ __forceinline__ void g1_row(const float* x, const float* w1, float* h1) {
#pragma unroll
    for (int o = 0; o < 64; o++) h1[o] = 0.f;
#pragma unroll
    for (int c = 0; c < 64; c++) {
        const float xc = x[c];
        const float* wr = w1 + c * 64;
#pragma unroll
        for (int o = 0; o < 64; o++) h1[o] = fmaf(xc, wr[o], h1[o]);
    }
}
__device__ __forceinline__ void g2_row(const float* x, const float* w2, float* h2) {
#pragma unroll
    for (int o = 0; o < 128; o++) h2[o] = 0.f;
#pragma unroll
    for (int c = 0; c < 64; c++) {
        const float xc = x[c];
        const float* wr = w2 + c * 128;
#pragma unroll
        for (int o = 0; o < 128; o++) h2[o] = fmaf(xc, wr[o], h2[o]);
    }
}
__device__ __forceinline__ void stats64_fold(float* h, int lane, int w, int t,
                                             float (*ssum)[64], float (*ssq)[64],
                                             float* dst) {
    float tmp[64];
#pragma unroll
    for (int i = 0; i < 64; i++) tmp[i] = h[i] * h[i];
    const float s = fold_sum_wave(h, lane);
    const float q = fold_sum_wave(tmp, lane);
    ssum[w][lane] = s; ssq[w][lane] = q;
    __syncthreads();
    if (t < 64) {
        dst[t] = ssum[0][t] + ssum[1][t] + ssum[2][t] + ssum[3][t];
        dst[128 + t] = ssq[0][t] + ssq[1][t] + ssq[2][t] + ssq[3][t];
    }
}
__device__ __forceinline__ void stats128_fold(float* h2, int lane, int w, int t,
                                              float (*ssum)[128], float (*ssq)[128],
                                              float* dst) {
    float tmp[64];
#pragma unroll
    for (int i = 0; i < 64; i++) tmp[i] = h2[i] * h2[i];
    const float sA = fold_sum_wave(h2, lane);
    const float qA = fold_sum_wave(tmp, lane);
    ssum[w][lane] = sA; ssq[w][lane] = qA;
#pragma unroll
    for (int i = 0; i < 64; i++) tmp[i] = h2[64 + i] * h2[64 + i];
    const float sB = fold_sum_wave(h2 + 64, lane);
    const float qB = fold_sum_wave(tmp, lane);
    ssum[w][64 + lane] = sB; ssq[w][64 + lane] = qB;
    __syncthreads();
    if (t < 128) {
        dst[t] = ssum[0][t] + ssum[1][t] + ssum[2][t] + ssum[3][t];
        dst[128 + t] = ssq[0][t] + ssq[1][t] + ssq[2][t] + ssq[3][t];
    }
}
__device__ __forceinline__ void max_out_r1(float* h2, int lane, int w, int blk,
                                           float* __restrict__ out_np) {
    const int qq = blk * 8 + w * 2 + (lane >> 5);
    float r0, r1;
    fold_max_half(h2, lane, r0, r1);
    out_np[(size_t)qq * 128 + (lane & 31)] = r0;
    out_np[(size_t)qq * 128 + 32 + (lane & 31)] = r1;
    fold_max_half(h2 + 64, lane, r0, r1);
    out_np[(size_t)qq * 128 + 64 + (lane & 31)] = r0;
    out_np[(size_t)qq * 128 + 96 + (lane & 31)] = r1;
}
__global__ __launch_bounds__(TPB_) void k_s0r(
    const float* __restrict__ points, const float* __restrict__ xyz,
    const float* __restrict__ newxyz, const int* __restrict__ ball,
    const float* __restrict__ W0T, float* __restrict__ partials) {
    __shared__ float w0[67 * 64];
    __shared__ float ssum[4][64], ssq[4][64];
    const int t = threadIdx.x, lane = t & 63, w = t >> 6;
    stage_w(w0, W0T, 67 * 64, t);
    __syncthreads();
    const int r = blockIdx.x * TPB_ + t;
    float h0[64];
    g0_row(points, xyz, newxyz, ball, w0, r, h0);
    stats64_fold(h0, lane, w, t, ssum, ssq, partials + (size_t)blockIdx.x * 256);
}
__global__ __launch_bounds__(TPB_) void k_s1r(
    const float* __restrict__ points, const float* __restrict__ xyz,
    const float* __restrict__ newxyz, const int* __restrict__ ball,
    const float* __restrict__ W0T, const float* __restrict__ W1T,
    const float* __restrict__ bnp, float* __restrict__ partials) {
    __shared__ float w0[67 * 64];
    __shared__ float w1[64 * 64];
    __shared__ float ssum[4][64], ssq[4][64];
    const int t = threadIdx.x, lane = t & 63, w = t >> 6;
    stage_w(w0, W0T, 67 * 64, t);
    stage_w(w1, W1T, 64 * 64, t);
    __syncthreads();
    const int r = blockIdx.x * TPB_ + t;
    float h0[64];
    g0_row(points, xyz, newxyz, ball, w0, r, h0);
    bn_relu<64>(h0, bnp, 0);
    float h1[64];
    g1_row(h0, w1, h1);
    stats64_fold(h1, lane, w, t, ssum, ssq, partials + (size_t)blockIdx.x * 256);
}
__global__ __launch_bounds__(TPB_) void k_s2r(
    const float* __restrict__ points, const float* __restrict__ xyz,
    const float* __restrict__ newxyz, const int* __restrict__ ball,
    const float* __restrict__ W0T, const float* __restrict__ W1T,
    const float* __restrict__ W2T, const float* __restrict__ bnp,
    float* __restrict__ partials) {
    __shared__ float w0[67 * 64];
    __shared__ float w1[64 * 64];
    __shared__ float w2[64 * 128];
    __shared__ float ssum[4][128], ssq[4][128];
    const int t = threadIdx.x, lane = t & 63, w = t >> 6;
    stage_w(w0, W0T, 67 * 64, t);
    stage_w(w1, W1T, 64 * 64, t);
    stage_w(w2, W2T, 64 * 128, t);
    __syncthreads();
    const int r = blockIdx.x * TPB_ + t;
    float h0[64];
    g0_row(points, xyz, newxyz, ball, w0, r, h0);
    bn_relu<64>(h0, bnp, 0);
    float h1[64];
    g1_row(h0, w1, h1);
    bn_relu<64>(h1, bnp, 256);
    float h2[128];
    g2_row(h1, w2, h2);
    stats128_fold(h2, lane, w, t, ssum, ssq, partials + (size_t)blockIdx.x * 256);
}
__global__ __launch_bounds__(TPB_) void k_s3r(
    const float* __restrict__ points, const float* __restrict__ xyz,
    const float* __restrict__ newxyz, const int* __restrict__ ball,
    const float* __restrict__ W0T, const float* __restrict__ W1T,
    const float* __restrict__ W2T, const float* __restrict__ bnp,
    float* __restrict__ out_np) {
    __shared__ float w0[67 * 64];
    __shared__ float w1[64 * 64];
    __shared__ float w2[64 * 128];
    const int t = threadIdx.x, lane = t & 63, w = t >> 6;
    stage_w(w0, W0T, 67 * 64, t);
    stage_w(w1, W1T, 64 * 64, t);
    stage_w(w2, W2T, 64 * 128, t);
    __syncthreads();
    const int r = blockIdx.x * TPB_ + t;
    float h0[64];
    g0_row(points, xyz, newxyz, ball, w0, r, h0);
    bn_relu<64>(h0, bnp, 0);
    float h1[64];
    g1_row(h0, w1, h1);
    bn_relu<64>(h1, bnp, 256);
    float h2[128];
    g2_row(h1, w2, h2);
    bn_relu<128>(h2, bnp, 512);
    max_out_r1(h2, lane, w, blockIdx.x, out_np);
}

// ---------------------------------------------------------------- BN finalize (parallel: 1 block/channel)
template <int C, int NB>
__global__ __launch_bounds__(256) void k_bnfin(const float* __restrict__ partials,
                                               const float* __restrict__ gw,
                                               const float* __restrict__ bw,
                                               float* __restrict__ bnpL) {
    const int ch = blockIdx.x;
    const int t = threadIdx.x;
    double s = 0.0, q = 0.0;
    for (int blk = t; blk < NB; blk += 256) {
        s += (double)partials[(size_t)blk * 256 + ch];
        q += (double)partials[(size_t)blk * 256 + 128 + ch];
    }
    __shared__ double ls[256], lq[256];
    ls[t] = s; lq[t] = q;
    __syncthreads();
    for (int off = 128; off >= 1; off >>= 1) {
        if (t < off) { ls[t] += ls[t + off]; lq[t] += lq[t + off]; }
        __syncthreads();
    }
    if (t == 0) {
        const double mean = ls[0] / (double)NROWS_;
        const double var = lq[0] / (double)NROWS_ - mean * mean;
        const float sc = (float)((double)gw[ch] / sqrt(var + 1e-5));
        const float sh = (float)((double)bw[ch] - mean * (double)sc);
        bnpL[ch] = sc;
        bnpL[128 + ch] = sh;
    }
}

// ---------------------------------------------------------------- launch
extern "C" void kernel_launch(void* const* d_in, const int* in_sizes, int n_in,
                              void* d_out, int out_size, void* d_ws, size_t ws_size,
                              hipStream_t stream) {
    const float* xyz = (const float*)d_in[0];
    const float* points = (const float*)d_in[1];
    const float* W0 = (const float*)d_in[2];
    const float* g0 = (const float*)d_in[3];
    const float* b0 = (const float*)d_in[4];
    const float* W1 = (const float*)d_in[5];
    const float* g1 = (const float*)d_in[6];
    const float* b1 = (const float*)d_in[7];
    const float* W2 = (const float*)d_in[8];
    const float* g2 = (const float*)d_in[9];
    const float* b2 = (const float*)d_in[10];

    float* out = (float*)d_out;
    float* newxyz = out;
    float* out_np = out + B_ * M_ * 3;

    char* ws = (char*)d_ws;
    float* sqn = (float*)(ws + OFF_SQN);
    int* fps_idx = (int*)(ws + OFF_FPS);
    int* ball = (int*)(ws + OFF_BALL);
    float* W0T = (float*)(ws + OFF_W0T);
    float* W1T = (float*)(ws + OFF_W1T);
    float* W2T = (float*)(ws + OFF_W2T);
    float* partials = (float*)(ws + OFF_PART);
    float* bnp = (float*)(ws + OFF_BNP);
    float* Ebuf = (float*)(ws + OFF_E);
    float* Dbuf = (float*)(ws + OFF_D);
    float* h1f = (float*)(ws + OFF_H1);
    unsigned short* h1h = (unsigned short*)(ws + OFF_H1);
    float* maxb = (float*)(ws + OFF_E);   // E dead after s1 -> reuse
    float* minb = maxb + (size_t)B_ * M_ * 128;

    const int cached = (ws_size >= NEED_B) ? 1 : 0;

    k_pre<<<PRE_NB, 512, 0, stream>>>(xyz, points, W0, W1, W2, Ebuf, sqn,
                                      W0T, W1T, W2T, cached);
    k_fps<<<B_, 512, 0, stream>>>(xyz, fps_idx);
    k_ndball<<<B_ * M_ / 4, 256, 0, stream>>>(xyz, sqn, fps_idx, W0T, newxyz,
                                              Dbuf, ball, cached);

    if (cached) {
        k_s0<<<NBLK2_, TPB_, 0, stream>>>(Ebuf, Dbuf, ball, partials);
        k_bnfin<64, NBLK2_><<<64, 256, 0, stream>>>(partials, g0, b0, bnp);
        if (ws_size >= NEED_A) {
            k_s1<1><<<NBLK2_, TPB_, 0, stream>>>(Ebuf, Dbuf, ball, W1T, bnp, partials, h1f, h1h);
            k_bnfin<64, NBLK2_><<<64, 256, 0, stream>>>(partials, g1, b1, bnp + 256);
            k_s2<1><<<NBLK2_, TPB_, 0, stream>>>(h1f, h1h, W2T, bnp, partials, maxb, minb);
        } else {
            k_s1<2><<<NBLK2_, TPB_, 0, stream>>>(Ebuf, Dbuf, ball, W1T, bnp, partials, h1f, h1h);
            k_bnfin<64, NBLK2_><<<64, 256, 0, stream>>>(partials, g1, b1, bnp + 256);
            k_s2<2><<<NBLK2_, TPB_, 0, stream>>>(h1f, h1h, W2T, bnp, partials, maxb, minb);
        }
        k_bnfin<128, NBLK2_><<<128, 256, 0, stream>>>(partials, g2, b2, bnp + 512);
        k_s3m<<<B_ * M_ * 128 / 256, 256, 0, stream>>>(maxb, minb, bnp, out_np);
    } else {
        k_s0r<<<NBLKM_, TPB_, 0, stream>>>(points, xyz, newxyz, ball, W0T, partials);
        k_bnfin<64, NBLKM_><<<64, 256, 0, stream>>>(partials, g0, b0, bnp);
        k_s1r<<<NBLKM_, TPB_, 0, stream>>>(points, xyz, newxyz, ball, W0T, W1T, bnp, partials);
        k_bnfin<64, NBLKM_><<<64, 256, 0, stream>>>(partials, g1, b1, bnp + 256);
        k_s2r<<<NBLKM_, TPB_, 0, stream>>>(points, xyz, newxyz, ball, W0T, W1T, W2T, bnp, partials);
        k_bnfin<128, NBLKM_><<<128, 256, 0, stream>>>(partials, g2, b2, bnp + 512);
        k_s3r<<<NBLKM_, TPB_, 0, stream>>>(points, xyz, newxyz, ball, W0T, W1T, W2T, bnp, out_np);
    }
}

// Round 15
// 1113.614 us; speedup vs baseline: 1.0310x; 1.0310x over previous
//
#include <hip/hip_runtime.h>
#include <hip/hip_bf16.h>
#include <cstdint>
#include <cstddef>

namespace {
constexpr int B_ = 16;
constexpr int N_ = 4096;
constexpr int D_ = 64;
constexpr int M_ = 1024;
constexpr int S_ = 32;
constexpr int NROWS_ = B_ * M_ * S_;        // 524288
constexpr int TPB_ = 256;
constexpr int NBLKM_ = NROWS_ / TPB_;       // 2048 (fallback, R=1)
constexpr int NBLK2_ = NROWS_ / (2 * TPB_); // 1024 (R=2)
constexpr float RR_ = 0.04f;

// fused fps+pre block roles
constexpr int FP_FPS = 16;    // batches
constexpr int FP_E   = 128;   // 65536 rows / 512
constexpr int FP_SQ  = 128;   // 65536 pts / 512
constexpr int FP_NB  = FP_FPS + FP_E + FP_SQ + 1;   // 273

// FPS shared-mem union: 37120 floats = 148480 B.  Only ~49 KB used; the big
// allocation blocks e_body (17 KB) from co-residing on FPS CUs
// (148480 + 17152 > 163840).
constexpr int FPS_SMEM = 37120;

// ws offsets (bytes)
constexpr size_t OFF_SQN  = 0;                                    // 262144
constexpr size_t OFF_FPS  = 262144;                               // 65536
constexpr size_t OFF_BALL = 327680;                               // 2097152
constexpr size_t OFF_W0T  = 2424832;                              // 17152
constexpr size_t OFF_W1T  = OFF_W0T + 67 * 64 * 4;                // 16384
constexpr size_t OFF_W2T  = OFF_W1T + 64 * 64 * 4;                // 32768
constexpr size_t OFF_PART = OFF_W2T + 64 * 128 * 4;               // 2048*256*4
constexpr size_t OFF_BNP  = OFF_PART + (size_t)NBLKM_ * 256 * 4;  // 3072
constexpr size_t OFF_E    = (OFF_BNP + 3072 + 255) & ~(size_t)255;
constexpr size_t E_SZ     = (size_t)B_ * N_ * 64 * 4;             // 16,777,216
constexpr size_t OFF_D    = OFF_E + E_SZ;
constexpr size_t D_SZ     = (size_t)B_ * M_ * 64 * 4;             // 4,194,304
constexpr size_t OFF_H1   = OFF_D + D_SZ;
constexpr size_t H1F_SZ   = (size_t)NROWS_ * 64 * 4;              // 134,217,728
constexpr size_t H1H_SZ   = (size_t)NROWS_ * 64 * 2;              // 67,108,864
constexpr size_t NEED_A   = OFF_H1 + H1F_SZ;                      // ~152.4 MiB
constexpr size_t NEED_B   = OFF_H1 + H1H_SZ;                      // ~88.4 MiB
}

// non-contractible multiply (separately-rounded product), scheduler-friendly
__device__ __forceinline__ float mul_nr(float a, float b) {
    float p = a * b;
    asm("" : "+v"(p));
    return p;
}
// volatile variant kept for the PROVEN-bitwise decision kernels (zero-risk)
__device__ __forceinline__ float mul_nf(float a, float b) {
    float p = a * b;
    asm volatile("" : "+v"(p));
    return p;
}

// DPP lane move (VALU-rate cross-lane)
template <int CTRL>
__device__ __forceinline__ float dpp_movf(float x) {
    return __int_as_float(
        __builtin_amdgcn_update_dpp(0, __float_as_int(x), CTRL, 0xF, 0xF, true));
}
__device__ __forceinline__ float xor_exch(float x, int k) {
    if (k == 0) return dpp_movf<0xB1>(x);   // quad_perm [1,0,3,2]
    if (k == 1) return dpp_movf<0x4E>(x);   // quad_perm [2,3,0,1]
    return __shfl_xor(x, 1 << k);
}

// ---------------------------------------------------------------- fold reduce
__device__ __forceinline__ float fold_sum_wave(float* cur, int lane) {
#pragma unroll
    for (int k = 0; k < 6; k++) {
        const bool hi = (lane >> k) & 1;
#pragma unroll
        for (int m = 0; m < (32 >> k); m++) {
            const float a = cur[2 * m], b = cur[2 * m + 1];
            const float keep = hi ? b : a;
            const float give = hi ? a : b;
            const float got = xor_exch(give, k);
            cur[m] = keep + got;
        }
    }
    return cur[0];
}
__device__ __forceinline__ float fold_sum32(float* cur, int lane) {
#pragma unroll
    for (int k = 0; k < 5; k++) {
        const bool hi = (lane >> k) & 1;
#pragma unroll
        for (int m = 0; m < (16 >> k); m++) {
            const float a = cur[2 * m], b = cur[2 * m + 1];
            const float keep = hi ? b : a;
            const float give = hi ? a : b;
            const float got = xor_exch(give, k);
            cur[m] = keep + got;
        }
    }
    return cur[0];
}
__device__ __forceinline__ float fold_max32(float* cur, int lane) {
#pragma unroll
    for (int k = 0; k < 5; k++) {
        const bool hi = (lane >> k) & 1;
#pragma unroll
        for (int m = 0; m < (16 >> k); m++) {
            const float a = cur[2 * m], b = cur[2 * m + 1];
            const float keep = hi ? b : a;
            const float give = hi ? a : b;
            const float got = xor_exch(give, k);
            cur[m] = fmaxf(keep, got);
        }
    }
    return cur[0];
}
__device__ __forceinline__ float fold_min32(float* cur, int lane) {
#pragma unroll
    for (int k = 0; k < 5; k++) {
        const bool hi = (lane >> k) & 1;
#pragma unroll
        for (int m = 0; m < (16 >> k); m++) {
            const float a = cur[2 * m], b = cur[2 * m + 1];
            const float keep = hi ? b : a;
            const float give = hi ? a : b;
            const float got = xor_exch(give, k);
            cur[m] = fminf(keep, got);
        }
    }
    return cur[0];
}

// bf16 pack/unpack (RNE)
__device__ __forceinline__ unsigned short f2bf(float f) {
    __hip_bfloat16 h = __float2bfloat16(f);
    return *reinterpret_cast<unsigned short*>(&h);
}
__device__ __forceinline__ float bf2f(unsigned short u) {
    __hip_bfloat16 h = *reinterpret_cast<__hip_bfloat16*>(&u);
    return __bfloat162float(h);
}

// ================================================================ fused FPS + prelude
// fps_body: byte-equivalent to the proven round-11 v2 kernel (570 us), just
// with pts/slots carved from the passed smem union.
__device__ void fps_body(const float* __restrict__ xyz, int* __restrict__ fps_idx,
                         float* smem, int b) {
    const int t = threadIdx.x;
    const int lane = t & 63, w = t >> 6;
    const float* xb = xyz + (size_t)b * N_ * 3;
    float* pts = smem;                                        // 12288 floats
    unsigned long long* slots = (unsigned long long*)(smem + 12288);  // 2*8 ull
    for (int i = t; i < N_ * 3; i += 512) pts[i] = xb[i];
    __syncthreads();

    const int n0 = t * 8;
    float px[8], py[8], pz[8], dist[8];
#pragma unroll
    for (int k = 0; k < 8; k++) {
        px[k] = pts[3 * (n0 + k)];
        py[k] = pts[3 * (n0 + k) + 1];
        pz[k] = pts[3 * (n0 + k) + 2];
        dist[k] = 1e10f;
    }

    int far = 0;
    for (int i = 0; i < M_; i++) {
        if (t == 0) fps_idx[b * M_ + i] = far;
        const float c0 = pts[3 * far], c1 = pts[3 * far + 1], c2 = pts[3 * far + 2];
        float bestv = -1.0f; int bestn = n0;
#pragma unroll
        for (int k = 0; k < 8; k++) {
            const float d0 = px[k] - c0, d1 = py[k] - c1, d2 = pz[k] - c2;
            const float dd = (mul_nr(d0, d0) + mul_nr(d1, d1)) + mul_nr(d2, d2);
            const float dm = fminf(dist[k], dd);
            dist[k] = dm;
            if (dm > bestv) { bestv = dm; bestn = n0 + k; }
        }
        float m = bestv;
        m = fmaxf(m, dpp_movf<0x111>(m));
        m = fmaxf(m, dpp_movf<0x112>(m));
        m = fmaxf(m, dpp_movf<0x114>(m));
        m = fmaxf(m, dpp_movf<0x118>(m));
        m = fmaxf(m, dpp_movf<0x142>(m));
        m = fmaxf(m, dpp_movf<0x143>(m));
        const float wmax = __int_as_float(
            __builtin_amdgcn_readlane(__float_as_int(m), 63));
        const unsigned long long mk = __ballot(bestv == wmax);
        const int src = __ffsll((long long)mk) - 1;
        const int wn = __builtin_amdgcn_readlane(bestn, src);
        if (lane == 0)
            slots[(i & 1) * 8 + w] =
                ((unsigned long long)__float_as_uint(wmax) << 32) | (unsigned)(~wn);
        __syncthreads();
        const unsigned long long* sl = slots + (i & 1) * 8;
        const unsigned long long s0 = sl[0], s1 = sl[1], s2 = sl[2], s3 = sl[3];
        const unsigned long long s4 = sl[4], s5 = sl[5], s6 = sl[6], s7 = sl[7];
        const unsigned long long a0 = s0 > s1 ? s0 : s1;
        const unsigned long long a1 = s2 > s3 ? s2 : s3;
        const unsigned long long a2 = s4 > s5 ? s4 : s5;
        const unsigned long long a3 = s6 > s7 ? s6 : s7;
        const unsigned long long b0 = a0 > a1 ? a0 : a1;
        const unsigned long long b1 = a2 > a3 ? a2 : a3;
        const unsigned long long bb = b0 > b1 ? b0 : b1;
        far = (int)(~(unsigned)bb);
    }
}

// E[n][o] = points[n]·W0p + xyz[n]·W0x  (self-transposes W0 from global)
__device__ void e_body(const float* __restrict__ points, const float* __restrict__ xyz,
                       const float* __restrict__ W0, float* __restrict__ E,
                       float* smem, int eb) {
    float* w0 = smem;                         // 4288 floats (17152 B)
    const int t = threadIdx.x;
    for (int i = t; i < 67 * 64; i += 512) {
        const int c = i >> 6, o = i & 63;
        w0[i] = W0[o * 67 + c];
    }
    __syncthreads();
    const int n = eb * 512 + t;               // 0..65535
    const float* prow = points + (size_t)n * 64;
    float h[64];
#pragma unroll
    for (int o = 0; o < 64; o++) h[o] = 0.f;
#pragma unroll
    for (int c = 0; c < 64; c += 4) {
        const float4 xv = *reinterpret_cast<const float4*>(prow + c);
        const float xs[4] = {xv.x, xv.y, xv.z, xv.w};
#pragma unroll
        for (int j = 0; j < 4; j++) {
            const float xc = xs[j];
            const float* wr = w0 + (c + j) * 64;
#pragma unroll
            for (int o = 0; o < 64; o++) h[o] = fmaf(xc, wr[o], h[o]);
        }
    }
    const float x0 = xyz[(size_t)n * 3], x1 = xyz[(size_t)n * 3 + 1], x2 = xyz[(size_t)n * 3 + 2];
#pragma unroll
    for (int o = 0; o < 64; o++) h[o] = fmaf(x0, w0[64 * 64 + o], h[o]);
#pragma unroll
    for (int o = 0; o < 64; o++) h[o] = fmaf(x1, w0[65 * 64 + o], h[o]);
#pragma unroll
    for (int o = 0; o < 64; o++) h[o] = fmaf(x2, w0[66 * 64 + o], h[o]);
    float4* dst = (float4*)(E + (size_t)n * 64);
#pragma unroll
    for (int j = 0; j < 16; j++)
        dst[j] = make_float4(h[4 * j], h[4 * j + 1], h[4 * j + 2], h[4 * j + 3]);
}

__device__ void sq_body(const float* __restrict__ xyz, float* __restrict__ sqn, int sb) {
    const int i = sb * 512 + threadIdx.x;     // 0..65535
    const float x = xyz[3 * i], y = xyz[3 * i + 1], z = xyz[3 * i + 2];
    sqn[i] = (mul_nf(x, x) + mul_nf(y, y)) + mul_nf(z, z);
}

__device__ void wt_body(const float* __restrict__ W0, const float* __restrict__ W1,
                        const float* __restrict__ W2, float* __restrict__ W0T,
                        float* __restrict__ W1T, float* __restrict__ W2T) {
    const int t = threadIdx.x;
    for (int i = t; i < 67 * 64; i += 512) { const int c = i >> 6, o = i & 63; W0T[i] = W0[o * 67 + c]; }
    for (int i = t; i < 64 * 64; i += 512) { const int c = i >> 6, o = i & 63; W1T[i] = W1[o * 64 + c]; }
    for (int i = t; i < 64 * 128; i += 512) { const int c = i >> 7, o = i & 127; W2T[i] = W2[o * 64 + c]; }
}

// fused: FPS (blocks 0-15, big-LDS guarded) ∥ E ∥ sqnorm ∥ weight-transpose.
// All bodies mutually independent; smem is a per-block union.
__global__ __launch_bounds__(512) void k_fpspre(
    const float* __restrict__ xyz, const float* __restrict__ points,
    const float* __restrict__ W0, const float* __restrict__ W1,
    const float* __restrict__ W2, int* __restrict__ fps_idx,
    float* __restrict__ E, float* __restrict__ sqn,
    float* __restrict__ W0T, float* __restrict__ W1T, float* __restrict__ W2T,
    int do_e) {
    __shared__ float smem[FPS_SMEM];          // 148480 B: blocks e_body co-residency
    const int blk = blockIdx.x;
    if (blk < FP_FPS) { fps_body(xyz, fps_idx, smem, blk); return; }
    if (blk < FP_FPS + FP_E) { if (do_e) e_body(points, xyz, W0, E, smem, blk - FP_FPS); return; }
    if (blk < FP_FPS + FP_E + FP_SQ) { sq_body(xyz, sqn, blk - FP_FPS - FP_E); return; }
    wt_body(W0, W1, W2, W0T, W1T, W2T);
}

// ---------------------------------------------------------------- newxyz + D + ball (fused; wave per q)
__global__ __launch_bounds__(256) void k_ndball(const float* __restrict__ xyz,
                                                const float* __restrict__ sqn,
                                                const int* __restrict__ fps_idx,
                                                const float* __restrict__ W0T,
                                                float* __restrict__ newxyz,
                                                float* __restrict__ Dq,
                                                int* __restrict__ ball, int do_d) {
    const int w = threadIdx.x >> 6, lane = threadIdx.x & 63;
    const int q = blockIdx.x * 4 + w;
    const int b = q >> 10;
    __shared__ int buf[4][32];
    const float* xb = xyz + (size_t)b * N_ * 3;
    const float* sb = sqn + (size_t)b * N_;
    const int f = fps_idx[q];
    const float* p = xyz + ((size_t)b * N_ + f) * 3;
    const float q0 = p[0], q1 = p[1], q2 = p[2];
    if (lane == 0) {
        newxyz[3 * q] = q0; newxyz[3 * q + 1] = q1; newxyz[3 * q + 2] = q2;
    }
    if (do_d) {
        const float wa = W0T[64 * 64 + lane];
        const float wb = W0T[65 * 64 + lane];
        const float wc = W0T[66 * 64 + lane];
        Dq[(size_t)q * 64 + lane] = fmaf(q2, wc, fmaf(q1, wb, q0 * wa));
    }
    const float sq = sb[f];

    int cnt = 0;
    for (int base = 0; base < N_ && cnt < 32; base += 64) {
        const int n = base + lane;
        const float p0 = xb[3 * n], p1 = xb[3 * n + 1], p2 = xb[3 * n + 2];
        float dot = fmaf(q2, p2, fmaf(q1, p1, q0 * p0));   // ascending FMA (proven)
        float tt = -2.0f * dot;
        tt = tt + sq;
        tt = tt + sb[n];
        const bool pred = !(tt > RR_);
        const unsigned long long mask = __ballot(pred);
        const int pos = cnt + __popcll(mask & ((1ull << lane) - 1ull));
        if (pred && pos < 32) buf[w][pos] = n;
        cnt += (int)__popcll(mask);
    }
    __syncthreads();
    if (lane < 32) {
        int e = buf[w][(lane < cnt) ? lane : 0];
        ball[(size_t)q * 32 + lane] = e;
    }
}

// ================================================================ helpers
__device__ __forceinline__ void stage_w(float* dst, const float* __restrict__ src,
                                        int n, int t) {
    for (int i = t; i < n; i += TPB_) dst[i] = src[i];
}

template <int NCH>
__device__ __forceinline__ void bn_relu(float* x, const float* __restrict__ bnp, int base) {
#pragma unroll
    for (int o = 0; o < NCH; o++)
        x[o] = fmaxf(0.f, fmaf(x[o], bnp[base + o], bnp[base + 128 + o]));
}

__device__ __forceinline__ void load_h0(float* x, const float* __restrict__ E,
                                        const float* __restrict__ Dq,
                                        const int* __restrict__ ball, int r) {
    const int b = r >> 15, q = r >> 5;
    const int g = ball[r];
    const float4* e = (const float4*)(E + ((size_t)(b * N_) + g) * 64);
    const float4* d = (const float4*)(Dq + (size_t)q * 64);
#pragma unroll
    for (int j = 0; j < 16; j++) {
        const float4 ev = e[j]; const float4 dv = d[j];
        x[4 * j + 0] = ev.x - dv.x; x[4 * j + 1] = ev.y - dv.y;
        x[4 * j + 2] = ev.z - dv.z; x[4 * j + 3] = ev.w - dv.w;
    }
}

__device__ __forceinline__ void h1_load_f32(float* x, const float* buf, int r) {
    const float4* src = (const float4*)(buf + (size_t)r * 64);
#pragma unroll
    for (int j = 0; j < 16; j++) {
        const float4 v = src[j];
        x[4 * j] = v.x; x[4 * j + 1] = v.y; x[4 * j + 2] = v.z; x[4 * j + 3] = v.w;
    }
}
__device__ __forceinline__ void h1_load_bf(float* x, const unsigned short* buf, int r) {
    const ushort4* src = (const ushort4*)(buf + (size_t)r * 64);
#pragma unroll
    for (int j = 0; j < 16; j++) {
        const ushort4 v = src[j];
        x[4 * j] = bf2f(v.x); x[4 * j + 1] = bf2f(v.y);
        x[4 * j + 2] = bf2f(v.z); x[4 * j + 3] = bf2f(v.w);
    }
}

// ================================================================ MLP stages (R=2)
__global__ __launch_bounds__(TPB_, 2) void k_s0(
    const float* __restrict__ E, const float* __restrict__ Dq,
    const int* __restrict__ ball, float* __restrict__ partials) {
    const int t = threadIdx.x, lane = t & 63, w = t >> 6;
    const int r0 = blockIdx.x * 512 + t, r1 = r0 + 256;
    __shared__ float ssum[4][64], ssq[4][64];
    float x0[64], x1[64];
    load_h0(x0, E, Dq, ball, r0);
    load_h0(x1, E, Dq, ball, r1);
#pragma unroll
    for (int i = 0; i < 64; i++) {
        const float sv_ = x0[i] + x1[i];
        x1[i] = x0[i] * x0[i] + x1[i] * x1[i];
        x0[i] = sv_;
    }
    const float sv = fold_sum_wave(x0, lane);
    const float qv = fold_sum_wave(x1, lane);
    ssum[w][lane] = sv; ssq[w][lane] = qv;
    __syncthreads();
    if (t < 64) {
        float* dst = partials + (size_t)blockIdx.x * 256;
        dst[t] = ssum[0][t] + ssum[1][t] + ssum[2][t] + ssum[3][t];
        dst[128 + t] = ssq[0][t] + ssq[1][t] + ssq[2][t] + ssq[3][t];
    }
}

template <int HST>
__global__ __launch_bounds__(TPB_, 2) void k_s1(
    const float* __restrict__ E, const float* __restrict__ Dq,
    const int* __restrict__ ball, const float* __restrict__ W1T,
    const float* __restrict__ bnp, float* __restrict__ partials,
    float* __restrict__ h1f, unsigned short* __restrict__ h1h) {
    __shared__ float w1[64 * 64];
    __shared__ float ssum[4][64], ssq[4][64];
    const int t = threadIdx.x, lane = t & 63, w = t >> 6;
    stage_w(w1, W1T, 64 * 64, t);
    const int r0 = blockIdx.x * 512 + t, r1 = r0 + 256;
    float x0[64], x1[64];
    load_h0(x0, E, Dq, ball, r0);
    bn_relu<64>(x0, bnp, 0);
    load_h0(x1, E, Dq, ball, r1);
    bn_relu<64>(x1, bnp, 0);
    __syncthreads();

#pragma unroll
    for (int tile = 0; tile < 2; tile++) {
        float a0[32], a1[32];
#pragma unroll
        for (int o = 0; o < 32; o++) { a0[o] = 0.f; a1[o] = 0.f; }
#pragma unroll
        for (int c = 0; c < 64; c++) {
            const float* wr = w1 + c * 64 + tile * 32;
            const float xc0 = x0[c], xc1 = x1[c];
#pragma unroll
            for (int o = 0; o < 32; o++) {
                a0[o] = fmaf(xc0, wr[o], a0[o]);
                a1[o] = fmaf(xc1, wr[o], a1[o]);
            }
        }
        if constexpr (HST == 1) {
            float4* d0 = (float4*)(h1f + (size_t)r0 * 64 + tile * 32);
            float4* d1 = (float4*)(h1f + (size_t)r1 * 64 + tile * 32);
#pragma unroll
            for (int j = 0; j < 8; j++) {
                d0[j] = make_float4(a0[4 * j], a0[4 * j + 1], a0[4 * j + 2], a0[4 * j + 3]);
                d1[j] = make_float4(a1[4 * j], a1[4 * j + 1], a1[4 * j + 2], a1[4 * j + 3]);
            }
        } else {
            ushort4* d0 = (ushort4*)(h1h + (size_t)r0 * 64 + tile * 32);
            ushort4* d1 = (ushort4*)(h1h + (size_t)r1 * 64 + tile * 32);
#pragma unroll
            for (int j = 0; j < 8; j++) {
                ushort4 v0, v1;
                v0.x = f2bf(a0[4 * j]); v0.y = f2bf(a0[4 * j + 1]);
                v0.z = f2bf(a0[4 * j + 2]); v0.w = f2bf(a0[4 * j + 3]);
                v1.x = f2bf(a1[4 * j]); v1.y = f2bf(a1[4 * j + 1]);
                v1.z = f2bf(a1[4 * j + 2]); v1.w = f2bf(a1[4 * j + 3]);
                d0[j] = v0; d1[j] = v1;
            }
        }
#pragma unroll
        for (int o = 0; o < 32; o++) {
            const float sv_ = a0[o] + a1[o];
            a1[o] = a0[o] * a0[o] + a1[o] * a1[o];
            a0[o] = sv_;
        }
        float sv = fold_sum32(a0, lane); sv += __shfl_xor(sv, 32);
        float qv = fold_sum32(a1, lane); qv += __shfl_xor(qv, 32);
        if (lane < 32) { ssum[w][tile * 32 + lane] = sv; ssq[w][tile * 32 + lane] = qv; }
    }
    __syncthreads();
    if (t < 64) {
        float* dst = partials + (size_t)blockIdx.x * 256;
        dst[t] = ssum[0][t] + ssum[1][t] + ssum[2][t] + ssum[3][t];
        dst[128 + t] = ssq[0][t] + ssq[1][t] + ssq[2][t] + ssq[3][t];
    }
}

template <int HLD>
__global__ __launch_bounds__(TPB_, 2) void k_s2(
    const float* __restrict__ h1f, const unsigned short* __restrict__ h1h,
    const float* __restrict__ W2T, const float* __restrict__ bnp,
    float* __restrict__ partials, float* __restrict__ maxb,
    float* __restrict__ minb) {
    __shared__ float w2[64 * 128];
    __shared__ float ssum[4][128], ssq[4][128];
    const int t = threadIdx.x, lane = t & 63, w = t >> 6;
    stage_w(w2, W2T, 64 * 128, t);
    const int r0 = blockIdx.x * 512 + t, r1 = r0 + 256;
    float x0[64], x1[64];
    if constexpr (HLD == 1) { h1_load_f32(x0, h1f, r0); h1_load_f32(x1, h1f, r1); }
    else { h1_load_bf(x0, h1h, r0); h1_load_bf(x1, h1h, r1); }
    bn_relu<64>(x0, bnp, 256);
    bn_relu<64>(x1, bnp, 256);
    __syncthreads();

    const int q0 = blockIdx.x * 16 + w * 2 + (lane >> 5);
#pragma unroll
    for (int tile = 0; tile < 4; tile++) {
        float a0[32], a1[32];
#pragma unroll
        for (int o = 0; o < 32; o++) { a0[o] = 0.f; a1[o] = 0.f; }
#pragma unroll
        for (int c = 0; c < 64; c++) {
            const float* wr = w2 + c * 128 + tile * 32;
            const float xc0 = x0[c], xc1 = x1[c];
#pragma unroll
            for (int o = 0; o < 32; o++) {
                a0[o] = fmaf(xc0, wr[o], a0[o]);
                a1[o] = fmaf(xc1, wr[o], a1[o]);
            }
        }
        {
            float c0[32];
#pragma unroll
            for (int o = 0; o < 32; o++) c0[o] = a0[o];
            const float mx = fold_max32(c0, lane);
#pragma unroll
            for (int o = 0; o < 32; o++) c0[o] = a0[o];
            const float mn = fold_min32(c0, lane);
            maxb[(size_t)q0 * 128 + tile * 32 + (lane & 31)] = mx;
            minb[(size_t)q0 * 128 + tile * 32 + (lane & 31)] = mn;
#pragma unroll
            for (int o = 0; o < 32; o++) c0[o] = a1[o];
            const float mx1 = fold_max32(c0, lane);
#pragma unroll
            for (int o = 0; o < 32; o++) c0[o] = a1[o];
            const float mn1 = fold_min32(c0, lane);
            maxb[(size_t)(q0 + 8) * 128 + tile * 32 + (lane & 31)] = mx1;
            minb[(size_t)(q0 + 8) * 128 + tile * 32 + (lane & 31)] = mn1;
        }
#pragma unroll
        for (int o = 0; o < 32; o++) {
            const float sv_ = a0[o] + a1[o];
            a1[o] = a0[o] * a0[o] + a1[o] * a1[o];
            a0[o] = sv_;
        }
        float sv = fold_sum32(a0, lane); sv += __shfl_xor(sv, 32);
        float qv = fold_sum32(a1, lane); qv += __shfl_xor(qv, 32);
        if (lane < 32) { ssum[w][tile * 32 + lane] = sv; ssq[w][tile * 32 + lane] = qv; }
    }
    __syncthreads();
    if (t < 128) {
        float* dst = partials + (size_t)blockIdx.x * 256;
        dst[t] = ssum[0][t] + ssum[1][t] + ssum[2][t] + ssum[3][t];
        dst[128 + t] = ssq[0][t] + ssq[1][t] + ssq[2][t] + ssq[3][t];
    }
}

// S3: elementwise epilogue (monotone-fma max/min select; bit-identical)
__global__ __launch_bounds__(256) void k_s3m(
    const float* __restrict__ maxb, const float* __restrict__ minb,
    const float* __restrict__ bnp, float* __restrict__ out_np) {
    const int i = blockIdx.x * 256 + threadIdx.x;
    const int ch = i & 127;
    const float sc = bnp[512 + ch], sh = bnp[512 + 128 + ch];
    const float h = (sc >= 0.f) ? maxb[i] : minb[i];
    out_np[i] = fmaxf(0.f, fmaf(h, sc, sh));
}

// ================================================================ fallback (R=1 recompute)
__device__ __forceinline__ void g0_row(
    const float* __restrict__ points, const float* __restrict__ xyz,
    const float* __restrict__ newxyz, const int* __restrict__ ball,
    const float* w0, int r, float* h0) {
    const int b = r >> 15;
    const int q = r >> 5;
    const int g = ball[r];
    const float* prow = points + ((size_t)(b * N_) + g) * D_;
    const float xg0 = xyz[((size_t)b * N_ + g) * 3 + 0] - newxyz[(size_t)q * 3 + 0];
    const float xg1 = xyz[((size_t)b * N_ + g) * 3 + 1] - newxyz[(size_t)q * 3 + 1];
    const float xg2 = xyz[((size_t)b * N_ + g) * 3 + 2] - newxyz[(size_t)q * 3 + 2];
#pragma unroll
    for (int o = 0; o < 64; o++) h0[o] = 0.f;
#pragma unroll
    for (int c = 0; c < 64; c += 4) {
        const float4 xv = *reinterpret_cast<const float4*>(prow + c);
        const float xs[4] = {xv.x, xv.y, xv.z, xv.w};
#pragma unroll
        for (int j = 0; j < 4; j++) {
            const float xc = xs[j];
            const float* wr = w0 + (c + j) * 64;
#pragma unroll
            for (int o = 0; o < 64; o++) h0[o] = fmaf(xc, wr[o], h0[o]);
        }
    }
#pragma unroll
    for (int o = 0; o < 64; o++) h0[o] = fmaf(xg0, w0[64 * 64 + o], h0[o]);
#pragma unroll
    for (int o = 0; o < 64; o++) h0[o] = fmaf(xg1, w0[65 * 64 + o], h0[o]);
#pragma unroll
    for (int o = 0; o < 64; o++) h0[o] = fmaf(xg2, w0[66 * 64 + o], h0[o]);
}
__device__ __forceinline__ void g1_row(const float* x, const float* w1, float* h1) {
#pragma unroll
    for (int o = 0; o < 64; o++) h1[o] = 0.f;
#pragma unroll
    for (int c = 0; c < 64; c++) {
        const float xc = x[c];
        const float* wr = w1 + c * 64;
#pragma unroll
        for (int o = 0; o < 64; o++) h1[o] = fmaf(xc, wr[o], h1[o]);
    }
}
__device__ __forceinline__ void g2_row(const float* x, const float* w2, float* h2) {
#pragma unroll
    for (int o = 0; o < 128; o++) h2[o] = 0.f;
#pragma unroll
    for (int c = 0; c < 64; c++) {
        const float xc = x[c];
        const float* wr = w2 + c * 128;
#pragma unroll
        for (int o = 0; o < 128; o++) h2[o] = fmaf(xc, wr[o], h2[o]);
    }
}
__device__ __forceinline__ void stats64_fold(float* h, int lane, int w, int t,
                                             float (*ssum)[64], float (*ssq)[64],
                                             float* dst) {
    float tmp[64];
#pragma unroll
    for (int i = 0; i < 64; i++) tmp[i] = h[i] * h[i];
    const float s = fold_sum_wave(h, lane);
    const float q = fold_sum_wave(tmp, lane);
    ssum[w][lane] = s; ssq[w][lane] = q;
    __syncthreads();
    if (t < 64) {
        dst[t] = ssum[0][t] + ssum[1][t] + ssum[2][t] + ssum[3][t];
        dst[128 + t] = ssq[0][t] + ssq[1][t] + ssq[2][t] + ssq[3][t];
    }
}
__device__ __forceinline__ void stats128_fold(float* h2, int lane, int w, int t,
                                              float (*ssum)[128], float (*ssq)[128],
                                              float* dst) {
    float tmp[64];
#pragma unroll
    for (int i = 0; i < 64; i++) tmp[i] = h2[i] * h2[i];
    const float sA = fold_sum_wave(h2, lane);
    const float qA = fold_sum_wave(tmp, lane);
    ssum[w][lane] = sA; ssq[w][lane] = qA;
#pragma unroll
    for (int i = 0; i < 64; i++) tmp[i] = h2[64 + i] * h2[64 + i];
    const float sB = fold_sum_wave(h2 + 64, lane);
    const float qB = fold_sum_wave(tmp, lane);
    ssum[w][64 + lane] = sB; ssq[w][64 + lane] = qB;
    __syncthreads();
    if (t < 128) {
        dst[t] = ssum[0][t] + ssum[1][t] + ssum[2][t] + ssum[3][t];
        dst[128 + t] = ssq[0][t] + ssq[1][t] + ssq[2][t] + ssq[3][t];
    }
}
__device__ __forceinline__ void fold_max_half(float* cur, int lane, float& r0, float& r1) {
#pragma unroll
    for (int k = 0; k < 5; k++) {
        const bool hi = (lane >> k) & 1;
#pragma unroll
        for (int m = 0; m < (32 >> k); m++) {
            const float a = cur[2 * m], b = cur[2 * m + 1];
            const float keep = hi ? b : a;
            const float give = hi ? a : b;
            const float got = xor_exch(give, k);
            cur[m] = fmaxf(keep, got);
        }
    }
    r0 = cur[0]; r1 = cur[1];
}
__device__ __forceinline__ void max_out_r1(float* h2, int lane, int w, int blk,
                                           float* __restrict__ out_np) {
    const int qq = blk * 8 + w * 2 + (lane >> 5);
    float r0, r1;
    fold_max_half(h2, lane, r0, r1);
    out_np[(size_t)qq * 128 + (lane & 31)] = r0;
    out_np[(size_t)qq * 128 + 32 + (lane & 31)] = r1;
    fold_max_half(h2 + 64, lane, r0, r1);
    out_np[(size_t)qq * 128 + 64 + (lane & 31)] = r0;
    out_np[(size_t)qq * 128 + 96 + (lane & 31)] = r1;
}
__global__ __launch_bounds__(TPB_) void k_s0r(
    const float* __restrict__ points, const float* __restrict__ xyz,
    const float* __restrict__ newxyz, const int* __restrict__ ball,
    const float* __restrict__ W0T, float* __restrict__ partials) {
    __shared__ float w0[67 * 64];
    __shared__ float ssum[4][64], ssq[4][64];
    const int t = threadIdx.x, lane = t & 63, w = t >> 6;
    stage_w(w0, W0T, 67 * 64, t);
    __syncthreads();
    const int r = blockIdx.x * TPB_ + t;
    float h0[64];
    g0_row(points, xyz, newxyz, ball, w0, r, h0);
    stats64_fold(h0, lane, w, t, ssum, ssq, partials + (size_t)blockIdx.x * 256);
}
__global__ __launch_bounds__(TPB_) void k_s1r(
    const float* __restrict__ points, const float* __restrict__ xyz,
    const float* __restrict__ newxyz, const int* __restrict__ ball,
    const float* __restrict__ W0T, const float* __restrict__ W1T,
    const float* __restrict__ bnp, float* __restrict__ partials) {
    __shared__ float w0[67 * 64];
    __shared__ float w1[64 * 64];
    __shared__ float ssum[4][64], ssq[4][64];
    const int t = threadIdx.x, lane = t & 63, w = t >> 6;
    stage_w(w0, W0T, 67 * 64, t);
    stage_w(w1, W1T, 64 * 64, t);
    __syncthreads();
    const int r = blockIdx.x * TPB_ + t;
    float h0[64];
    g0_row(points, xyz, newxyz, ball, w0, r, h0);
    bn_relu<64>(h0, bnp, 0);
    float h1[64];
    g1_row(h0, w1, h1);
    stats64_fold(h1, lane, w, t, ssum, ssq, partials + (size_t)blockIdx.x * 256);
}
__global__ __launch_bounds__(TPB_) void k_s2r(
    const float* __restrict__ points, const float* __restrict__ xyz,
    const float* __restrict__ newxyz, const int* __restrict__ ball,
    const float* __restrict__ W0T, const float* __restrict__ W1T,
    const float* __restrict__ W2T, const float* __restrict__ bnp,
    float* __restrict__ partials) {
    __shared__ float w0[67 * 64];
    __shared__ float w1[64 * 64];
    __shared__ float w2[64 * 128];
    __shared__ float ssum[4][128], ssq[4][128];
    const int t = threadIdx.x, lane = t & 63, w = t >> 6;
    stage_w(w0, W0T, 67 * 64, t);
    stage_w(w1, W1T, 64 * 64, t);
    stage_w(w2, W2T, 64 * 128, t);
    __syncthreads();
    const int r = blockIdx.x * TPB_ + t;
    float h0[64];
    g0_row(points, xyz, newxyz, ball, w0, r, h0);
    bn_relu<64>(h0, bnp, 0);
    float h1[64];
    g1_row(h0, w1, h1);
    bn_relu<64>(h1, bnp, 256);
    float h2[128];
    g2_row(h1, w2, h2);
    stats128_fold(h2, lane, w, t, ssum, ssq, partials + (size_t)blockIdx.x * 256);
}
__global__ __launch_bounds__(TPB_) void k_s3r(
    const float* __restrict__ points, const float* __restrict__ xyz,
    const float* __restrict__ newxyz, const int* __restrict__ ball,
    const float* __restrict__ W0T, const float* __restrict__ W1T,
    const float* __restrict__ W2T, const float* __restrict__ bnp,
    float* __restrict__ out_np) {
    __shared__ float w0[67 * 64];
    __shared__ float w1[64 * 64];
    __shared__ float w2[64 * 128];
    const int t = threadIdx.x, lane = t & 63, w = t >> 6;
    stage_w(w0, W0T, 67 * 64, t);
    stage_w(w1, W1T, 64 * 64, t);
    stage_w(w2, W2T, 64 * 128, t);
    __syncthreads();
    const int r = blockIdx.x * TPB_ + t;
    float h0[64];
    g0_row(points, xyz, newxyz, ball, w0, r, h0);
    bn_relu<64>(h0, bnp, 0);
    float h1[64];
    g1_row(h0, w1, h1);
    bn_relu<64>(h1, bnp, 256);
    float h2[128];
    g2_row(h1, w2, h2);
    bn_relu<128>(h2, bnp, 512);
    max_out_r1(h2, lane, w, blockIdx.x, out_np);
}

// ---------------------------------------------------------------- BN finalize (parallel: 1 block/channel)
template <int C, int NB>
__global__ __launch_bounds__(256) void k_bnfin(const float* __restrict__ partials,
                                               const float* __restrict__ gw,
                                               const float* __restrict__ bw,
                                               float* __restrict__ bnpL) {
    const int ch = blockIdx.x;
    const int t = threadIdx.x;
    double s = 0.0, q = 0.0;
    for (int blk = t; blk < NB; blk += 256) {
        s += (double)partials[(size_t)blk * 256 + ch];
        q += (double)partials[(size_t)blk * 256 + 128 + ch];
    }
    __shared__ double ls[256], lq[256];
    ls[t] = s; lq[t] = q;
    __syncthreads();
    for (int off = 128; off >= 1; off >>= 1) {
        if (t < off) { ls[t] += ls[t + off]; lq[t] += lq[t + off]; }
        __syncthreads();
    }
    if (t == 0) {
        const double mean = ls[0] / (double)NROWS_;
        const double var = lq[0] / (double)NROWS_ - mean * mean;
        const float sc = (float)((double)gw[ch] / sqrt(var + 1e-5));
        const float sh = (float)((double)bw[ch] - mean * (double)sc);
        bnpL[ch] = sc;
        bnpL[128 + ch] = sh;
    }
}

// ---------------------------------------------------------------- launch
extern "C" void kernel_launch(void* const* d_in, const int* in_sizes, int n_in,
                              void* d_out, int out_size, void* d_ws, size_t ws_size,
                              hipStream_t stream) {
    const float* xyz = (const float*)d_in[0];
    const float* points = (const float*)d_in[1];
    const float* W0 = (const float*)d_in[2];
    const float* g0 = (const float*)d_in[3];
    const float* b0 = (const float*)d_in[4];
    const float* W1 = (const float*)d_in[5];
    const float* g1 = (const float*)d_in[6];
    const float* b1 = (const float*)d_in[7];
    const float* W2 = (const float*)d_in[8];
    const float* g2 = (const float*)d_in[9];
    const float* b2 = (const float*)d_in[10];

    float* out = (float*)d_out;
    float* newxyz = out;
    float* out_np = out + B_ * M_ * 3;

    char* ws = (char*)d_ws;
    float* sqn = (float*)(ws + OFF_SQN);
    int* fps_idx = (int*)(ws + OFF_FPS);
    int* ball = (int*)(ws + OFF_BALL);
    float* W0T = (float*)(ws + OFF_W0T);
    float* W1T = (float*)(ws + OFF_W1T);
    float* W2T = (float*)(ws + OFF_W2T);
    float* partials = (float*)(ws + OFF_PART);
    float* bnp = (float*)(ws + OFF_BNP);
    float* Ebuf = (float*)(ws + OFF_E);
    float* Dbuf = (float*)(ws + OFF_D);
    float* h1f = (float*)(ws + OFF_H1);
    unsigned short* h1h = (unsigned short*)(ws + OFF_H1);
    float* maxb = (float*)(ws + OFF_E);   // E dead after s1 -> reuse
    float* minb = maxb + (size_t)B_ * M_ * 128;

    const int cached = (ws_size >= NEED_B) ? 1 : 0;

    k_fpspre<<<FP_NB, 512, 0, stream>>>(xyz, points, W0, W1, W2, fps_idx,
                                        Ebuf, sqn, W0T, W1T, W2T, cached);
    k_ndball<<<B_ * M_ / 4, 256, 0, stream>>>(xyz, sqn, fps_idx, W0T, newxyz,
                                              Dbuf, ball, cached);

    if (cached) {
        k_s0<<<NBLK2_, TPB_, 0, stream>>>(Ebuf, Dbuf, ball, partials);
        k_bnfin<64, NBLK2_><<<64, 256, 0, stream>>>(partials, g0, b0, bnp);
        if (ws_size >= NEED_A) {
            k_s1<1><<<NBLK2_, TPB_, 0, stream>>>(Ebuf, Dbuf, ball, W1T, bnp, partials, h1f, h1h);
            k_bnfin<64, NBLK2_><<<64, 256, 0, stream>>>(partials, g1, b1, bnp + 256);
            k_s2<1><<<NBLK2_, TPB_, 0, stream>>>(h1f, h1h, W2T, bnp, partials, maxb, minb);
        } else {
            k_s1<2><<<NBLK2_, TPB_, 0, stream>>>(Ebuf, Dbuf, ball, W1T, bnp, partials, h1f, h1h);
            k_bnfin<64, NBLK2_><<<64, 256, 0, stream>>>(partials, g1, b1, bnp + 256);
            k_s2<2><<<NBLK2_, TPB_, 0, stream>>>(h1f, h1h, W2T, bnp, partials, maxb, minb);
        }
        k_bnfin<128, NBLK2_><<<128, 256, 0, stream>>>(partials, g2, b2, bnp + 512);
        k_s3m<<<B_ * M_ * 128 / 256, 256, 0, stream>>>(maxb, minb, bnp, out_np);
    } else {
        k_s0r<<<NBLKM_, TPB_, 0, stream>>>(points, xyz, newxyz, ball, W0T, partials);
        k_bnfin<64, NBLKM_><<<64, 256, 0, stream>>>(partials, g0, b0, bnp);
        k_s1r<<<NBLKM_, TPB_, 0, stream>>>(points, xyz, newxyz, ball, W0T, W1T, bnp, partials);
        k_bnfin<64, NBLKM_><<<64, 256, 0, stream>>>(partials, g1, b1, bnp + 256);
        k_s2r<<<NBLKM_, TPB_, 0, stream>>>(points, xyz, newxyz, ball, W0T, W1T, W2T, bnp, partials);
        k_bnfin<128, NBLKM_><<<128, 256, 0, stream>>>(partials, g2, b2, bnp + 512);
        k_s3r<<<NBLKM_, TPB_, 0, stream>>>(points, xyz, newxyz, ball, W0T, W1T, W2T, bnp, out_np);
    }
}